// Round 2
// baseline (5536.698 us; speedup 1.0000x reference)
//
#include <hip/hip_runtime.h>

#define SS 4096
#define TT 2048

// clang native vector type: usable directly in asm "v" constraints
typedef float v4f __attribute__((ext_vector_type(4)));

// ---------- LLC-coherent (agent) memory ops, hand-rolled ----------
// sc0 sc1 => bypass non-coherent per-XCD L2, serve at Infinity Cache.

__device__ __forceinline__ void llc_load4x4(const v4f* p,
                                            v4f& a, v4f& b, v4f& c, v4f& d) {
  asm volatile(
      "global_load_dwordx4 %0, %4, off sc0 sc1\n\t"
      "global_load_dwordx4 %1, %5, off sc0 sc1\n\t"
      "global_load_dwordx4 %2, %6, off sc0 sc1\n\t"
      "global_load_dwordx4 %3, %7, off sc0 sc1\n\t"
      "s_waitcnt vmcnt(0)"
      : "=&v"(a), "=&v"(b), "=&v"(c), "=&v"(d)
      : "v"(p), "v"(p + 256), "v"(p + 512), "v"(p + 768)
      : "memory");
}

// store + vmcnt(0): drain needed so the compiler can't reuse the data VGPRs
// while the store is still in flight (and LLC visibility is prompt).
__device__ __forceinline__ void llc_store4_drain(v4f* p, v4f v) {
  asm volatile("global_store_dwordx4 %0, %1, off sc0 sc1\n\t"
               "s_waitcnt vmcnt(0)"
               :: "v"(p), "v"(v) : "memory");
}

// ---------- helpers ----------

// OR of (sign-adjusted) words: ready iff top bit of result is 0
__device__ __forceinline__ unsigned orsgn(v4f v, unsigned e) {
  return (__float_as_uint(v.x) ^ e) | (__float_as_uint(v.y) ^ e)
       | (__float_as_uint(v.z) ^ e) | (__float_as_uint(v.w) ^ e);
}

__device__ __forceinline__ uint4 xorsgn(v4f v, unsigned e) {
  uint4 r;
  r.x = __float_as_uint(v.x) ^ e;  r.y = __float_as_uint(v.y) ^ e;
  r.z = __float_as_uint(v.z) ^ e;  r.w = __float_as_uint(v.w) ^ e;
  return r;
}

// ---------- kernel A: q0 = exp(log_M0 + log_emit[0]) (positive = sign for t=0) ----------
__global__ void init_q(const float* __restrict__ m0, const float* __restrict__ emit,
                       float* __restrict__ q) {
  int i = blockIdx.x * 256 + threadIdx.x;
  q[i] = __expf(m0[i] + emit[i]);
}

// ---------- kernel B: persistent forward recursion ----------
// 256 blocks x 256 threads, 1 block/CU. Block b owns rows [16b,16b+16).
// E-slice lives in f32 registers. Round-1 lesson (VGPR_Count=152): an
// er[64] ARRAY goes to scratch (SROA refuses ~1KB aggregates) -> every
// step re-read scratch with zero latency hiding. Fix: 64 NAMED v4f
// variables, macro-expanded, statically indexed everywhere. ~320 VGPR
// demand fits the 512-reg budget at 1 wave/EU (launch_bounds(256,1)).
// Lane (wave w, lane l) owns rows [16b+4w, +4) x cols {k*256 + 4l .. +4},
// k=0..15 -> q read is one contiguous v4f per k (conflict-free 16B/lane).
// Step parity lives in the sign bit of q (writer at step t stores q * s_t,
// s_t = ((t>>1)&1)? -1 : +1; 0xAA workspace poison is negative).
#define K16(X) X(0) X(1) X(2) X(3) X(4) X(5) X(6) X(7) \
               X(8) X(9) X(10) X(11) X(12) X(13) X(14) X(15)

#define EXP4(v) (v4f){__expf((v).x), __expf((v).y), __expf((v).z), __expf((v).w)}

__global__ void __launch_bounds__(256, 1)
hmm_fwd(const float* __restrict__ lt, const float* __restrict__ emit,
        float* q, float* out) {
  __shared__ float qs[SS];                 // 16 KiB
  __shared__ float wsum[4];
  const int b    = blockIdx.x;
  const int tid  = threadIdx.x;
  const int wave = tid >> 6;
  const int lane = tid & 63;
  const int row0 = (b << 4) + (wave << 2);

  // 64 named E registers: e{r}_{k} = exp(log_trans[row0+r][k*256+4l .. +4])
#define DECL_E(k) v4f e0_##k, e1_##k, e2_##k, e3_##k;
  K16(DECL_E)
#undef DECL_E

  {
    const float* s0 = lt + (size_t)row0 * SS + (lane << 2);
    const float* s1 = s0 + SS;
    const float* s2 = s1 + SS;
    const float* s3 = s2 + SS;
#define INIT_E(k) { \
    v4f t0 = *(const v4f*)(s0 + ((k) << 8)); \
    v4f t1 = *(const v4f*)(s1 + ((k) << 8)); \
    v4f t2 = *(const v4f*)(s2 + ((k) << 8)); \
    v4f t3 = *(const v4f*)(s3 + ((k) << 8)); \
    e0_##k = EXP4(t0); e1_##k = EXP4(t1); \
    e2_##k = EXP4(t2); e3_##k = EXP4(t3); }
    K16(INIT_E)
#undef INIT_E
  }

  for (int t = 1; t <= TT; ++t) {
    // issue emit load before the poll: HBM latency hides under the LLC wait
    v4f em;
    if (lane == 0) em = *(const v4f*)(emit + (size_t)t * SS + row0);

    // poll q_{t-1} data directly: expected stored-sign of step t-1
    const unsigned e = (unsigned)(((t - 1) >> 1) & 1) << 31;
    {
      const v4f* qsrc4 = (const v4f*)(q + ((t - 1) & 1) * SS);
      v4f va, vb, vc, vd;
      for (;;) {
        llc_load4x4(qsrc4 + tid, va, vb, vc, vd);
        unsigned o = orsgn(va, e) | orsgn(vb, e) | orsgn(vc, e) | orsgn(vd, e);
        if (!(o >> 31)) break;   // all 16 words carry step-(t-1) sign
      }
      uint4* qs4 = (uint4*)qs;   // strip sign exactly via XOR
      qs4[tid]       = xorsgn(va, e);
      qs4[tid + 256] = xorsgn(vb, e);
      qs4[tid + 512] = xorsgn(vc, e);
      qs4[tid + 768] = xorsgn(vd, e);
    }
    __syncthreads();

    // GEMV from registers: 4 rows per lane, one v4f of q per k (16 LDS reads)
    v4f a0 = {0.f, 0.f, 0.f, 0.f}, a1 = a0, a2 = a0, a3 = a0;
    const v4f* qv4 = (const v4f*)qs;
#define FMA_K(k) { \
    v4f qv = qv4[((k) << 6) + lane]; \
    a0 += e0_##k * qv;  a1 += e1_##k * qv; \
    a2 += e2_##k * qv;  a3 += e3_##k * qv; }
    K16(FMA_K)
#undef FMA_K

    float acc0 = (a0.x + a0.y) + (a0.z + a0.w);
    float acc1 = (a1.x + a1.y) + (a1.z + a1.w);
    float acc2 = (a2.x + a2.y) + (a2.z + a2.w);
    float acc3 = (a3.x + a3.y) + (a3.z + a3.w);
#pragma unroll
    for (int m = 32; m > 0; m >>= 1) {
      acc0 += __shfl_xor(acc0, m);
      acc1 += __shfl_xor(acc1, m);
      acc2 += __shfl_xor(acc2, m);
      acc3 += __shfl_xor(acc3, m);
    }

    // publish q_t chunk with step-t sign folded into the scale; no flags
    float* qdst = q + (t & 1) * SS;
    if (lane == 0) {
      float scale = ((t & 255) == 0) ? 0x1p-46f : 1.0f;    // exact pow2 renorm
      if ((t >> 1) & 1) scale = -scale;                     // embed parity sign
      v4f r;
      r.x = acc0 * (__expf(em.x) * scale);
      r.y = acc1 * (__expf(em.y) * scale);
      r.z = acc2 * (__expf(em.z) * scale);
      r.w = acc3 * (__expf(em.w) * scale);
      llc_store4_drain((v4f*)(qdst + row0), r);
    }
    __syncthreads();   // qs stable until all waves finished GEMV reads
  }

  // final reduction: q_T (t=2048) in buffer 0, stored sign positive
  if (b == 0) {
    const v4f* qf4 = (const v4f*)q;
    v4f va, vb, vc, vd;
    for (;;) {
      llc_load4x4(qf4 + tid, va, vb, vc, vd);
      unsigned o = orsgn(va, 0) | orsgn(vb, 0) | orsgn(vc, 0) | orsgn(vd, 0);
      if (!(o >> 31)) break;
    }
    float s = va.x + va.y + va.z + va.w + vb.x + vb.y + vb.z + vb.w
            + vc.x + vc.y + vc.z + vc.w + vd.x + vd.y + vd.z + vd.w;
#pragma unroll
    for (int m = 32; m > 0; m >>= 1) s += __shfl_xor(s, m);
    if (lane == 0) wsum[wave] = s;
    __syncthreads();
    if (tid == 0) {
      float tot = wsum[0] + wsum[1] + wsum[2] + wsum[3];
      out[0] = logf(tot) + 368.0f * 0.693147180559945f;   // 8 rescales * 46 * ln2
    }
  }
}

// ---------- launch ----------
extern "C" void kernel_launch(void* const* d_in, const int* in_sizes, int n_in,
                              void* d_out, int out_size, void* d_ws, size_t ws_size,
                              hipStream_t stream) {
  const float* log_M0    = (const float*)d_in[0];
  const float* log_trans = (const float*)d_in[1];
  const float* log_emit  = (const float*)d_in[2];
  // d_in[3] = T (fixed 2048, unused)

  float* q   = (float*)d_ws;     // 2 x 16 KiB (poisoned 0xAA = negative)
  float* out = (float*)d_out;

  hipLaunchKernelGGL(init_q, dim3(SS / 256), dim3(256), 0, stream, log_M0, log_emit, q);
  hipLaunchKernelGGL(hmm_fwd, dim3(256), dim3(256), 0, stream, log_trans, log_emit, q, out);
}

// Round 3
// 5058.585 us; speedup vs baseline: 1.0945x; 1.0945x over previous
//
#include <hip/hip_runtime.h>

#define SS 4096
#define TT 2048

// clang native vector types: usable directly in asm "v" constraints
typedef float v4f __attribute__((ext_vector_type(4)));
typedef unsigned u2 __attribute__((ext_vector_type(2)));

// ---------- LLC-coherent (agent) memory ops, hand-rolled ----------
// sc0 sc1 => bypass non-coherent per-XCD L2, serve at Infinity Cache.

__device__ __forceinline__ void llc_load4x4(const v4f* p,
                                            v4f& a, v4f& b, v4f& c, v4f& d) {
  asm volatile(
      "global_load_dwordx4 %0, %4, off sc0 sc1\n\t"
      "global_load_dwordx4 %1, %5, off sc0 sc1\n\t"
      "global_load_dwordx4 %2, %6, off sc0 sc1\n\t"
      "global_load_dwordx4 %3, %7, off sc0 sc1\n\t"
      "s_waitcnt vmcnt(0)"
      : "=&v"(a), "=&v"(b), "=&v"(c), "=&v"(d)
      : "v"(p), "v"(p + 256), "v"(p + 512), "v"(p + 768)
      : "memory");
}

// store + vmcnt(0): drain needed so the compiler can't reuse the data VGPRs
// while the store is still in flight (and LLC visibility is prompt).
__device__ __forceinline__ void llc_store4_drain(v4f* p, v4f v) {
  asm volatile("global_store_dwordx4 %0, %1, off sc0 sc1\n\t"
               "s_waitcnt vmcnt(0)"
               :: "v"(p), "v"(v) : "memory");
}

// ---------- helpers ----------

__device__ __forceinline__ unsigned short f2bf_rn(float f) {
  unsigned int u = __float_as_uint(f);
  u += 0x7FFFu + ((u >> 16) & 1u);   // RNE; inputs positive finite
  return (unsigned short)(u >> 16);
}

__device__ __forceinline__ unsigned pkbf(float a, float b) {
  return (unsigned)f2bf_rn(a) | ((unsigned)f2bf_rn(b) << 16);
}

__device__ __forceinline__ float blo(unsigned w) { return __uint_as_float(w << 16); }
__device__ __forceinline__ float bhi(unsigned w) { return __uint_as_float(w & 0xFFFF0000u); }

// 4 MACs: packed-bf16 E pair-of-pairs vs f32 q vector, f32 accumulate
__device__ __forceinline__ v4f fma4(u2 e, v4f q, v4f a) {
  a.x = fmaf(blo(e.x), q.x, a.x);
  a.y = fmaf(bhi(e.x), q.y, a.y);
  a.z = fmaf(blo(e.y), q.z, a.z);
  a.w = fmaf(bhi(e.y), q.w, a.w);
  return a;
}

// OR of (sign-adjusted) words: ready iff top bit of result is 0
__device__ __forceinline__ unsigned orsgn(v4f v, unsigned e) {
  return (__float_as_uint(v.x) ^ e) | (__float_as_uint(v.y) ^ e)
       | (__float_as_uint(v.z) ^ e) | (__float_as_uint(v.w) ^ e);
}

__device__ __forceinline__ uint4 xorsgn(v4f v, unsigned e) {
  uint4 r;
  r.x = __float_as_uint(v.x) ^ e;  r.y = __float_as_uint(v.y) ^ e;
  r.z = __float_as_uint(v.z) ^ e;  r.w = __float_as_uint(v.w) ^ e;
  return r;
}

// ---------- kernel A: q0 = exp(log_M0 + log_emit[0]) (positive = sign for t=0) ----------
__global__ void init_q(const float* __restrict__ m0, const float* __restrict__ emit,
                       float* __restrict__ q) {
  int i = blockIdx.x * 256 + threadIdx.x;
  q[i] = __expf(m0[i] + emit[i]);
}

// ---------- kernel B: persistent forward recursion ----------
// 256 blocks x 256 threads, 1 block/CU. Block b owns rows [16b,16b+16).
// Round-1/2 lesson: f32 E (256 VGPR/lane) exceeds the allocator's budget
// (VGPR_Count stuck at 152, E spilled to scratch both times). This round:
//   (a) E as PACKED BF16 in 64 named u2 regs = 128 VGPRs/lane (fits arch 256)
//   (b) amdgpu_waves_per_eu(1,1): clamp the occupancy target to the true
//       launch shape (4 waves/CU) so regalloc gets the whole file.
// Numerics identical to the round-0 kernel that passed absmax 0.0
// (RNE bf16 E, f32 q, f32 fma) -- but E now streams from registers, not
// 128KB/step of LDS. Unpack = 1 shift/AND per FMA.
// Lane (wave w, lane l) owns rows [16b+4w, +4) x cols {k*256 + 4l .. +4},
// k=0..15 -> q read is one contiguous v4f per k (conflict-free 16B/lane).
// Step parity lives in the sign bit of q (writer at step t stores q * s_t,
// s_t = ((t>>1)&1)? -1 : +1; 0xAA workspace poison is negative).
#define K16(X) X(0) X(1) X(2) X(3) X(4) X(5) X(6) X(7) \
               X(8) X(9) X(10) X(11) X(12) X(13) X(14) X(15)

__global__ void __launch_bounds__(256, 1) __attribute__((amdgpu_waves_per_eu(1, 1)))
hmm_fwd(const float* __restrict__ lt, const float* __restrict__ emit,
        float* q, float* out) {
  __shared__ float qs[SS];                 // 16 KiB
  __shared__ float wsum[4];
  const int b    = blockIdx.x;
  const int tid  = threadIdx.x;
  const int wave = tid >> 6;
  const int lane = tid & 63;
  const int row0 = (b << 4) + (wave << 2);

  // 64 named packed-bf16 E registers:
  // e{r}_{k} = bf16(exp(log_trans[row0+r][k*256+4l .. +4])), 2x2 packed
#define DECL_E(k) u2 e0_##k, e1_##k, e2_##k, e3_##k;
  K16(DECL_E)
#undef DECL_E

  {
    const float* s0 = lt + (size_t)row0 * SS + (lane << 2);
    const float* s1 = s0 + SS;
    const float* s2 = s1 + SS;
    const float* s3 = s2 + SS;
#define INIT_E(k) { \
    v4f t0 = *(const v4f*)(s0 + ((k) << 8)); \
    v4f t1 = *(const v4f*)(s1 + ((k) << 8)); \
    v4f t2 = *(const v4f*)(s2 + ((k) << 8)); \
    v4f t3 = *(const v4f*)(s3 + ((k) << 8)); \
    e0_##k = (u2){pkbf(__expf(t0.x), __expf(t0.y)), pkbf(__expf(t0.z), __expf(t0.w))}; \
    e1_##k = (u2){pkbf(__expf(t1.x), __expf(t1.y)), pkbf(__expf(t1.z), __expf(t1.w))}; \
    e2_##k = (u2){pkbf(__expf(t2.x), __expf(t2.y)), pkbf(__expf(t2.z), __expf(t2.w))}; \
    e3_##k = (u2){pkbf(__expf(t3.x), __expf(t3.y)), pkbf(__expf(t3.z), __expf(t3.w))}; }
    K16(INIT_E)
#undef INIT_E
  }

  for (int t = 1; t <= TT; ++t) {
    // issue emit load before the poll: HBM latency hides under the LLC wait
    v4f em;
    if (lane == 0) em = *(const v4f*)(emit + (size_t)t * SS + row0);

    // poll q_{t-1} data directly: expected stored-sign of step t-1
    const unsigned e = (unsigned)(((t - 1) >> 1) & 1) << 31;
    {
      const v4f* qsrc4 = (const v4f*)(q + ((t - 1) & 1) * SS);
      v4f va, vb, vc, vd;
      for (;;) {
        llc_load4x4(qsrc4 + tid, va, vb, vc, vd);
        unsigned o = orsgn(va, e) | orsgn(vb, e) | orsgn(vc, e) | orsgn(vd, e);
        if (!(o >> 31)) break;   // all 16 words carry step-(t-1) sign
      }
      uint4* qs4 = (uint4*)qs;   // strip sign exactly via XOR
      qs4[tid]       = xorsgn(va, e);
      qs4[tid + 256] = xorsgn(vb, e);
      qs4[tid + 512] = xorsgn(vc, e);
      qs4[tid + 768] = xorsgn(vd, e);
    }
    __syncthreads();

    // GEMV: 4 rows per lane from bf16 registers, one v4f of q per k (16 LDS reads)
    v4f a0 = {0.f, 0.f, 0.f, 0.f}, a1 = a0, a2 = a0, a3 = a0;
    const v4f* qv4 = (const v4f*)qs;
#define FMA_K(k) { \
    v4f qv = qv4[((k) << 6) + lane]; \
    a0 = fma4(e0_##k, qv, a0);  a1 = fma4(e1_##k, qv, a1); \
    a2 = fma4(e2_##k, qv, a2);  a3 = fma4(e3_##k, qv, a3); }
    K16(FMA_K)
#undef FMA_K

    float acc0 = (a0.x + a0.y) + (a0.z + a0.w);
    float acc1 = (a1.x + a1.y) + (a1.z + a1.w);
    float acc2 = (a2.x + a2.y) + (a2.z + a2.w);
    float acc3 = (a3.x + a3.y) + (a3.z + a3.w);
#pragma unroll
    for (int m = 32; m > 0; m >>= 1) {
      acc0 += __shfl_xor(acc0, m);
      acc1 += __shfl_xor(acc1, m);
      acc2 += __shfl_xor(acc2, m);
      acc3 += __shfl_xor(acc3, m);
    }

    // publish q_t chunk with step-t sign folded into the scale; no flags
    float* qdst = q + (t & 1) * SS;
    if (lane == 0) {
      float scale = ((t & 255) == 0) ? 0x1p-46f : 1.0f;    // exact pow2 renorm
      if ((t >> 1) & 1) scale = -scale;                     // embed parity sign
      v4f r;
      r.x = acc0 * (__expf(em.x) * scale);
      r.y = acc1 * (__expf(em.y) * scale);
      r.z = acc2 * (__expf(em.z) * scale);
      r.w = acc3 * (__expf(em.w) * scale);
      llc_store4_drain((v4f*)(qdst + row0), r);
    }
    __syncthreads();   // qs stable until all waves finished GEMV reads
  }

  // final reduction: q_T (t=2048) in buffer 0, stored sign positive
  if (b == 0) {
    const v4f* qf4 = (const v4f*)q;
    v4f va, vb, vc, vd;
    for (;;) {
      llc_load4x4(qf4 + tid, va, vb, vc, vd);
      unsigned o = orsgn(va, 0) | orsgn(vb, 0) | orsgn(vc, 0) | orsgn(vd, 0);
      if (!(o >> 31)) break;
    }
    float s = va.x + va.y + va.z + va.w + vb.x + vb.y + vb.z + vb.w
            + vc.x + vc.y + vc.z + vc.w + vd.x + vd.y + vd.z + vd.w;
#pragma unroll
    for (int m = 32; m > 0; m >>= 1) s += __shfl_xor(s, m);
    if (lane == 0) wsum[wave] = s;
    __syncthreads();
    if (tid == 0) {
      float tot = wsum[0] + wsum[1] + wsum[2] + wsum[3];
      out[0] = logf(tot) + 368.0f * 0.693147180559945f;   // 8 rescales * 46 * ln2
    }
  }
}

// ---------- launch ----------
extern "C" void kernel_launch(void* const* d_in, const int* in_sizes, int n_in,
                              void* d_out, int out_size, void* d_ws, size_t ws_size,
                              hipStream_t stream) {
  const float* log_M0    = (const float*)d_in[0];
  const float* log_trans = (const float*)d_in[1];
  const float* log_emit  = (const float*)d_in[2];
  // d_in[3] = T (fixed 2048, unused)

  float* q   = (float*)d_ws;     // 2 x 16 KiB (poisoned 0xAA = negative)
  float* out = (float*)d_out;

  hipLaunchKernelGGL(init_q, dim3(SS / 256), dim3(256), 0, stream, log_M0, log_emit, q);
  hipLaunchKernelGGL(hmm_fwd, dim3(256), dim3(256), 0, stream, log_trans, log_emit, q, out);
}